// Round 1
// baseline (311.905 us; speedup 1.0000x reference)
//
#include <hip/hip_runtime.h>
#include <math.h>

#define EPS 1e-5f

__device__ __forceinline__ float wave_sum(float v) {
  v += __shfl_down(v, 32);
  v += __shfl_down(v, 16);
  v += __shfl_down(v, 8);
  v += __shfl_down(v, 4);
  v += __shfl_down(v, 2);
  v += __shfl_down(v, 1);
  return v;
}

__device__ __forceinline__ float silu_f(float v) { return v / (1.f + __expf(-v)); }
__device__ __forceinline__ float sigm_f(float v) { return 1.f / (1.f + __expf(-v)); }

// ---------------------------------------------------------------------------
// Kernel A: per-(b,c) 64x64 2D DFT magnitude mean + spatial mean.
// Separable DFT with twiddle tables; Re1/Im1 stored [kv][h] stride 65 to
// break bank conflicts in the column pass.
// ---------------------------------------------------------------------------
__global__ __launch_bounds__(256) void k_dft(const float* __restrict__ x,
                                             float* __restrict__ energy,
                                             float* __restrict__ meanx) {
  __shared__ float xs[4096];
  __shared__ float re1[64 * 65];
  __shared__ float im1[64 * 65];
  __shared__ float tc[64];
  __shared__ float ts[64];
  __shared__ float redA[4], redB[4];
  const int bc = blockIdx.x;       // b*64 + c
  const int tid = threadIdx.x;
  const float* xp = x + (size_t)bc * 4096;
  float lsum = 0.f;
#pragma unroll
  for (int i = 0; i < 16; ++i) {
    float v = xp[tid + i * 256];
    xs[tid + i * 256] = v;
    lsum += v;
  }
  if (tid < 64) {
    float ang = 6.283185307179586f * (float)tid / 64.f;
    tc[tid] = cosf(ang);
    ts[tid] = sinf(ang);
  }
  __syncthreads();
  // stage 1: DFT along w.  output (h, kv)
#pragma unroll 1
  for (int i = 0; i < 16; ++i) {
    int o = tid + i * 256;
    int h = o >> 6, kv = o & 63;
    const float* row = &xs[h * 64];
    float re = 0.f, im = 0.f;
#pragma unroll
    for (int w = 0; w < 64; ++w) {
      float v = row[w];
      int t = (w * kv) & 63;
      re = fmaf(v, tc[t], re);
      im = fmaf(v, -ts[t], im);
    }
    re1[kv * 65 + h] = re;
    im1[kv * 65 + h] = im;
  }
  __syncthreads();
  // stage 2: DFT along h.  output (ku, kv); accumulate |X|
  float msum = 0.f;
#pragma unroll 1
  for (int i = 0; i < 16; ++i) {
    int o = tid + i * 256;
    int ku = o >> 6, kv = o & 63;
    float re = 0.f, im = 0.f;
#pragma unroll
    for (int h = 0; h < 64; ++h) {
      int t = (h * ku) & 63;
      float c = tc[t], s = ts[t];
      float a = re1[kv * 65 + h], b = im1[kv * 65 + h];
      re = fmaf(a, c, fmaf(b, s, re));
      im = fmaf(b, c, fmaf(-a, s, im));
    }
    msum += sqrtf(re * re + im * im);
  }
  msum = wave_sum(msum);
  lsum = wave_sum(lsum);
  int wid = tid >> 6;
  if ((tid & 63) == 0) { redA[wid] = msum; redB[wid] = lsum; }
  __syncthreads();
  if (tid == 0) {
    float e = redA[0] + redA[1] + redA[2] + redA[3];
    float m = redB[0] + redB[1] + redB[2] + redB[3];
    energy[bc] = e * (1.f / 4096.f);
    meanx[bc] = m * (1.f / 4096.f);
  }
}

// ---------------------------------------------------------------------------
// Kernel B: per-batch channel attention head. One block per b, 64 threads
// (one per channel). Produces s2[b,c] = g*a_f + (1-g)*a_x.
// ---------------------------------------------------------------------------
__global__ __launch_bounds__(64) void k_attn(
    const float* __restrict__ energy, const float* __restrict__ meanx,
    const float* __restrict__ ex_w, const float* __restrict__ ey_w,
    const float* __restrict__ ez_w, const float* __restrict__ ff_w,
    const float* __restrict__ ff_b, const float* __restrict__ g1_w,
    const float* __restrict__ g1_b, const float* __restrict__ g2_w,
    const float* __restrict__ g2_b, float* __restrict__ s2) {
  __shared__ float e[64], mx[64], my[64], mz[64];
  __shared__ float ax[64], ay[64], az[64], af[64], h1[16];
  const int b = blockIdx.x;
  const int c = threadIdx.x;
  e[c] = energy[b * 64 + c];
  mx[c] = meanx[b * 64 + c];
  __syncthreads();
  // rank = #{c': e[c'] > e[c]} + #{c'<c: e[c'] == e[c]}  (stable argsort of -e)
  int rank = 0;
  float ec = e[c];
  for (int i = 0; i < 64; ++i) {
    float ei = e[i];
    rank += (ei > ec) || (ei == ec && i < c);
  }
  float mask = (rank < 32) ? 1.f : 0.f;
  my[c] = mx[c] * mask;
  mz[c] = mx[c] * (1.f - mask);
  __syncthreads();
  {
    float l, r, m;
    l = (c > 0) ? mx[c - 1] : 0.f; m = mx[c]; r = (c < 63) ? mx[c + 1] : 0.f;
    ax[c] = sigm_f(ex_w[0] * l + ex_w[1] * m + ex_w[2] * r);
    l = (c > 0) ? my[c - 1] : 0.f; m = my[c]; r = (c < 63) ? my[c + 1] : 0.f;
    ay[c] = sigm_f(ey_w[0] * l + ey_w[1] * m + ey_w[2] * r);
    l = (c > 0) ? mz[c - 1] : 0.f; m = mz[c]; r = (c < 63) ? mz[c + 1] : 0.f;
    az[c] = sigm_f(ez_w[0] * l + ez_w[1] * m + ez_w[2] * r);
  }
  __syncthreads();
  // a_f: grouped 1x1 on concat([a_y, a_z]); group g reads concat chans [g*32, g*32+32)
  {
    int g = c >> 4;
    float acc = ff_b[c];
#pragma unroll
    for (int i = 0; i < 32; ++i) {
      int ch = g * 32 + i;
      float v = (ch < 64) ? ay[ch] : az[ch - 64];
      acc = fmaf(v, ff_w[c * 32 + i], acc);
    }
    af[c] = acc;
  }
  __syncthreads();
  if (c < 16) {
    float a = g1_b[c];
#pragma unroll
    for (int i = 0; i < 64; ++i) a = fmaf(af[i], g1_w[c * 128 + i], a);
#pragma unroll
    for (int i = 0; i < 64; ++i) a = fmaf(ax[i], g1_w[c * 128 + 64 + i], a);
    h1[c] = silu_f(a);
  }
  __syncthreads();
  float gv = g2_b[c];
#pragma unroll
  for (int o = 0; o < 16; ++o) gv = fmaf(h1[o], g2_w[c * 16 + o], gv);
  gv = sigm_f(gv);
  s2[b * 64 + c] = gv * af[c] + (1.f - gv) * ax[c];
}

// ---------------------------------------------------------------------------
// Kernel C: fused ReceptiveFieldAttentionConv.
// Pixel-shuffle + stride-3 conv == per-pixel reduction over (ic_in_group, j).
// Block = (b, group g of 16 ch, tile of 4 rows); thread = pixel.
// ---------------------------------------------------------------------------
__global__ __launch_bounds__(256) void k_rfa(
    const float* __restrict__ x,
    const float* __restrict__ sc_w, const float* __restrict__ sc_b,
    const float* __restrict__ ac_w, const float* __restrict__ ac_b,
    const float* __restrict__ oc_w, const float* __restrict__ oc_b,
    const float* __restrict__ bn_g, const float* __restrict__ bn_b,
    const float* __restrict__ bn_m, const float* __restrict__ bn_v,
    float* __restrict__ xrfa) {
  __shared__ float scw_l[1296];
  __shared__ float scb_l[144];
  __shared__ float acw_l[144];
  __shared__ float acb_l[144];
  __shared__ float ocw_l[2304];
  __shared__ float ocb_l[16];
  __shared__ float bns_l[16];
  __shared__ float bnb_l[16];
  const int blk = blockIdx.x;
  const int tile = blk & 15;
  const int g = (blk >> 4) & 3;
  const int b = blk >> 6;
  const int tid = threadIdx.x;
  for (int i = tid; i < 1296; i += 256) scw_l[i] = sc_w[g * 1296 + i];
  if (tid < 144) {
    scb_l[tid] = sc_b[g * 144 + tid];
    acw_l[tid] = ac_w[g * 144 + tid];
    acb_l[tid] = ac_b[g * 144 + tid];
  }
  for (int i = tid; i < 2304; i += 256) ocw_l[i] = oc_w[g * 2304 + i];
  if (tid < 16) {
    int oc = g * 16 + tid;
    float s = bn_g[oc] * rsqrtf(bn_v[oc] + EPS);
    bns_l[tid] = s;
    bnb_l[tid] = bn_b[oc] - bn_m[oc] * s;
    ocb_l[tid] = oc_b[oc];
  }
  __syncthreads();
  const int h = tile * 4 + (tid >> 6);
  const int w = tid & 63;
  float acc[16];
#pragma unroll
  for (int i = 0; i < 16; ++i) acc[i] = 0.f;
  const bool tN = h > 0, tS = h < 63, tW = w > 0, tE = w < 63;
  const float* xb = x + ((size_t)(b * 64 + g * 16)) * 4096 + h * 64 + w;
#pragma unroll 1
  for (int icg = 0; icg < 16; ++icg) {
    const float* xc = xb + icg * 4096;
    float nb[9];
    nb[0] = (tN && tW) ? xc[-65] : 0.f;
    nb[1] = tN ? xc[-64] : 0.f;
    nb[2] = (tN && tE) ? xc[-63] : 0.f;
    nb[3] = tW ? xc[-1] : 0.f;
    nb[4] = xc[0];
    nb[5] = tE ? xc[1] : 0.f;
    nb[6] = (tS && tW) ? xc[63] : 0.f;
    nb[7] = tS ? xc[64] : 0.f;
    nb[8] = (tS && tE) ? xc[65] : 0.f;
    float ap = (nb[0] + nb[1] + nb[2] + nb[3] + nb[4] + nb[5] + nb[6] + nb[7] + nb[8]) * (1.f / 9.f);
    float f[9], a[9];
    float amax = -1e30f;
#pragma unroll
    for (int j = 0; j < 9; ++j) {
      const float* wj = &scw_l[(icg * 9 + j) * 9];
      float pre = scb_l[icg * 9 + j];
#pragma unroll
      for (int t = 0; t < 9; ++t) pre = fmaf(nb[t], wj[t], pre);
      f[j] = silu_f(pre);
      float av = fmaf(ap, acw_l[icg * 9 + j], acb_l[icg * 9 + j]);
      a[j] = av;
      amax = fmaxf(amax, av);
    }
    float esum = 0.f;
    float p[9];
#pragma unroll
    for (int j = 0; j < 9; ++j) {
      float ev = __expf(a[j] - amax);
      esum += ev;
      p[j] = f[j] * ev;
    }
    float inv = 1.f / esum;
#pragma unroll
    for (int j = 0; j < 9; ++j) p[j] *= inv;
#pragma unroll
    for (int oco = 0; oco < 16; ++oco) {
      const float* wv = &ocw_l[(oco * 16 + icg) * 9];
      float s = 0.f;
#pragma unroll
      for (int j = 0; j < 9; ++j) s = fmaf(p[j], wv[j], s);
      acc[oco] += s;
    }
  }
  float* op = xrfa + ((size_t)(b * 64 + g * 16)) * 4096 + h * 64 + w;
#pragma unroll
  for (int oco = 0; oco < 16; ++oco) {
    float v = acc[oco] + ocb_l[oco];
    v = fmaf(v, bns_l[oco], bnb_l[oco]);
    op[oco * 4096] = silu_f(v);
  }
}

// ---------------------------------------------------------------------------
// Kernel D: final 1x1 conv over concat([x_rfa, x*s2]) + BN + SiLU.
// ---------------------------------------------------------------------------
__global__ __launch_bounds__(128) void k_fuse(
    const float* __restrict__ x, const float* __restrict__ xrfa,
    const float* __restrict__ s2, const float* __restrict__ fu_w,
    const float* __restrict__ fu_b, const float* __restrict__ bn_g,
    const float* __restrict__ bn_b, const float* __restrict__ bn_m,
    const float* __restrict__ bn_v, float* __restrict__ out) {
  __shared__ float fw[4096];
  __shared__ float s2l[64];
  __shared__ float fub[32], bns[32], bnb[32];
  const int blk = blockIdx.x;
  const int tile = blk & 31;
  const int b = blk >> 5;
  const int tid = threadIdx.x;
  for (int i = tid; i < 4096; i += 128) fw[i] = fu_w[i];
  if (tid < 64) s2l[tid] = s2[b * 64 + tid];
  if (tid < 32) {
    float s = bn_g[tid] * rsqrtf(bn_v[tid] + EPS);
    bns[tid] = s;
    bnb[tid] = bn_b[tid] - bn_m[tid] * s;
    fub[tid] = fu_b[tid];
  }
  __syncthreads();
  const int h = tile * 2 + (tid >> 6);
  const int w = tid & 63;
  const int sp = h * 64 + w;
  float acc[32];
#pragma unroll
  for (int i = 0; i < 32; ++i) acc[i] = 0.f;
  const float* xr = xrfa + (size_t)b * 64 * 4096 + sp;
  const float* xp = x + (size_t)b * 64 * 4096 + sp;
#pragma unroll 4
  for (int c = 0; c < 64; ++c) {
    float v = xr[c * 4096];
#pragma unroll
    for (int oc = 0; oc < 32; ++oc) acc[oc] = fmaf(v, fw[oc * 128 + c], acc[oc]);
  }
#pragma unroll 4
  for (int c = 0; c < 64; ++c) {
    float v = xp[c * 4096] * s2l[c];
#pragma unroll
    for (int oc = 0; oc < 32; ++oc) acc[oc] = fmaf(v, fw[oc * 128 + 64 + c], acc[oc]);
  }
  float* op = out + (size_t)b * 32 * 4096 + sp;
#pragma unroll
  for (int oc = 0; oc < 32; ++oc) {
    float v = acc[oc] + fub[oc];
    v = fmaf(v, bns[oc], bnb[oc]);
    op[oc * 4096] = silu_f(v);
  }
}

extern "C" void kernel_launch(void* const* d_in, const int* in_sizes, int n_in,
                              void* d_out, int out_size, void* d_ws, size_t ws_size,
                              hipStream_t stream) {
  const float* x       = (const float*)d_in[0];
  const float* sc_w    = (const float*)d_in[1];
  const float* sc_b    = (const float*)d_in[2];
  const float* ac_w    = (const float*)d_in[3];
  const float* ac_b    = (const float*)d_in[4];
  const float* oc_w    = (const float*)d_in[5];
  const float* oc_b    = (const float*)d_in[6];
  const float* oc_bn_g = (const float*)d_in[7];
  const float* oc_bn_b = (const float*)d_in[8];
  const float* oc_bn_m = (const float*)d_in[9];
  const float* oc_bn_v = (const float*)d_in[10];
  const float* ex_w    = (const float*)d_in[11];
  const float* ey_w    = (const float*)d_in[12];
  const float* ez_w    = (const float*)d_in[13];
  const float* ff_w    = (const float*)d_in[14];
  const float* ff_b    = (const float*)d_in[15];
  const float* g1_w    = (const float*)d_in[16];
  const float* g1_b    = (const float*)d_in[17];
  const float* g2_w    = (const float*)d_in[18];
  const float* g2_b    = (const float*)d_in[19];
  const float* fu_w    = (const float*)d_in[20];
  const float* fu_b    = (const float*)d_in[21];
  const float* fu_bn_g = (const float*)d_in[22];
  const float* fu_bn_b = (const float*)d_in[23];
  const float* fu_bn_m = (const float*)d_in[24];
  const float* fu_bn_v = (const float*)d_in[25];

  float* ws     = (float*)d_ws;
  float* energy = ws;            // 512 floats
  float* meanx  = ws + 512;      // 512 floats
  float* s2     = ws + 1024;     // 512 floats
  float* xrfa   = ws + 2048;     // 8*64*4096 = 2097152 floats

  k_dft<<<512, 256, 0, stream>>>(x, energy, meanx);
  k_attn<<<8, 64, 0, stream>>>(energy, meanx, ex_w, ey_w, ez_w,
                               ff_w, ff_b, g1_w, g1_b, g2_w, g2_b, s2);
  k_rfa<<<512, 256, 0, stream>>>(x, sc_w, sc_b, ac_w, ac_b, oc_w, oc_b,
                                 oc_bn_g, oc_bn_b, oc_bn_m, oc_bn_v, xrfa);
  k_fuse<<<256, 128, 0, stream>>>(x, xrfa, s2, fu_w, fu_b,
                                  fu_bn_g, fu_bn_b, fu_bn_m, fu_bn_v,
                                  (float*)d_out);
}

// Round 2
// 223.836 us; speedup vs baseline: 1.3935x; 1.3935x over previous
//
#include <hip/hip_runtime.h>
#include <math.h>

#define EPS 1e-5f

__device__ __forceinline__ float wave_sum(float v) {
  v += __shfl_down(v, 32);
  v += __shfl_down(v, 16);
  v += __shfl_down(v, 8);
  v += __shfl_down(v, 4);
  v += __shfl_down(v, 2);
  v += __shfl_down(v, 1);
  return v;
}

__device__ __forceinline__ float silu_f(float v) { return v / (1.f + __expf(-v)); }
__device__ __forceinline__ float sigm_f(float v) { return 1.f / (1.f + __expf(-v)); }

// ---------------------------------------------------------------------------
// Kernel A: per-(b,c) mean |2D-DFT| + spatial mean, via wave-level radix-2
// DIF FFT. 64 lanes = one 64-sample line; 6 butterfly stages via __shfl_xor
// (wave64 ds_bpermute). Twiddles live in 12 registers/lane — no LDS twiddle
// traffic. DIF leaves outputs bit-reversed, which is irrelevant: we only sum
// |X| over all bins, and the lane<->bin mapping is identical for every row,
// so the column pass still transforms true columns. Magnitude is
// conj-invariant so the twiddle sign convention cannot affect the result.
// LDS intermediate stored at stride 65: bank = (col+lane)%32 -> 2-way (free).
// ---------------------------------------------------------------------------
__global__ __launch_bounds__(256) void k_dft(const float* __restrict__ x,
                                             float* __restrict__ energy,
                                             float* __restrict__ meanx) {
  __shared__ float re1[64 * 65];
  __shared__ float im1[64 * 65];
  __shared__ float redA[4], redB[4];
  const int bc = blockIdx.x;       // b*64 + c
  const int tid = threadIdx.x;
  const int lane = tid & 63;
  const int wv = tid >> 6;         // wave 0..3
  const float* xp = x + (size_t)bc * 4096;

  // Per-lane twiddles for the 6 DIF stages.
  // Stage s: half = 32>>s; upper lanes (lane&half) multiply by
  // W = exp(-i * 2*pi * ((lane & (half-1)) << s) / 64); lower lanes by 1.
  float twc[6], tws[6];
#pragma unroll
  for (int s = 0; s < 6; ++s) {
    int half = 32 >> s;
    if (lane & half) {
      float ang = -6.283185307179586f * (float)((lane & (half - 1)) << s) / 64.f;
      float sv, cv;
      __sincosf(ang, &sv, &cv);
      twc[s] = cv;
      tws[s] = sv;
    } else {
      twc[s] = 1.f;
      tws[s] = 0.f;
    }
  }

  // ---- row pass: FFT along w, 2 rows per iteration for ILP ----
  float lsum = 0.f;
#pragma unroll 1
  for (int rp = 0; rp < 8; ++rp) {
    const int h0 = wv * 16 + rp * 2;
    float ar = xp[h0 * 64 + lane];
    float br = xp[(h0 + 1) * 64 + lane];
    lsum += ar + br;
    float ai = 0.f, bi = 0.f;
#pragma unroll
    for (int s = 0; s < 6; ++s) {
      const int half = 32 >> s;
      const bool up = (lane & half) != 0;
      float par = __shfl_xor(ar, half);
      float pai = __shfl_xor(ai, half);
      float pbr = __shfl_xor(br, half);
      float pbi = __shfl_xor(bi, half);
      float tar = up ? par - ar : ar + par;
      float tai = up ? pai - ai : ai + pai;
      float tbr = up ? pbr - br : br + pbr;
      float tbi = up ? pbi - bi : bi + pbi;
      const float c = twc[s], sn = tws[s];
      ar = tar * c - tai * sn;
      ai = tar * sn + tai * c;
      br = tbr * c - tbi * sn;
      bi = tbr * sn + tbi * c;
    }
    // lane position == frequency slot (bit-reversed kv, consistent per row)
    re1[lane * 65 + h0] = ar;
    im1[lane * 65 + h0] = ai;
    re1[lane * 65 + h0 + 1] = br;
    im1[lane * 65 + h0 + 1] = bi;
  }
  __syncthreads();

  // ---- column pass: FFT along h for each frequency slot, 2 cols/iter ----
  float msum = 0.f;
#pragma unroll 1
  for (int cp = 0; cp < 8; ++cp) {
    const int c0 = wv * 16 + cp * 2;
    float ar = re1[c0 * 65 + lane];
    float ai = im1[c0 * 65 + lane];
    float br = re1[(c0 + 1) * 65 + lane];
    float bi = im1[(c0 + 1) * 65 + lane];
#pragma unroll
    for (int s = 0; s < 6; ++s) {
      const int half = 32 >> s;
      const bool up = (lane & half) != 0;
      float par = __shfl_xor(ar, half);
      float pai = __shfl_xor(ai, half);
      float pbr = __shfl_xor(br, half);
      float pbi = __shfl_xor(bi, half);
      float tar = up ? par - ar : ar + par;
      float tai = up ? pai - ai : ai + pai;
      float tbr = up ? pbr - br : br + pbr;
      float tbi = up ? pbi - bi : bi + pbi;
      const float c = twc[s], sn = tws[s];
      ar = tar * c - tai * sn;
      ai = tar * sn + tai * c;
      br = tbr * c - tbi * sn;
      bi = tbr * sn + tbi * c;
    }
    msum += sqrtf(ar * ar + ai * ai) + sqrtf(br * br + bi * bi);
  }

  msum = wave_sum(msum);
  lsum = wave_sum(lsum);
  if (lane == 0) { redA[wv] = msum; redB[wv] = lsum; }
  __syncthreads();
  if (tid == 0) {
    float e = redA[0] + redA[1] + redA[2] + redA[3];
    float m = redB[0] + redB[1] + redB[2] + redB[3];
    energy[bc] = e * (1.f / 4096.f);
    meanx[bc] = m * (1.f / 4096.f);
  }
}

// ---------------------------------------------------------------------------
// Kernel B: per-batch channel attention head. One block per b, 64 threads
// (one per channel). Produces s2[b,c] = g*a_f + (1-g)*a_x.
// ---------------------------------------------------------------------------
__global__ __launch_bounds__(64) void k_attn(
    const float* __restrict__ energy, const float* __restrict__ meanx,
    const float* __restrict__ ex_w, const float* __restrict__ ey_w,
    const float* __restrict__ ez_w, const float* __restrict__ ff_w,
    const float* __restrict__ ff_b, const float* __restrict__ g1_w,
    const float* __restrict__ g1_b, const float* __restrict__ g2_w,
    const float* __restrict__ g2_b, float* __restrict__ s2) {
  __shared__ float e[64], mx[64], my[64], mz[64];
  __shared__ float ax[64], ay[64], az[64], af[64], h1[16];
  const int b = blockIdx.x;
  const int c = threadIdx.x;
  e[c] = energy[b * 64 + c];
  mx[c] = meanx[b * 64 + c];
  __syncthreads();
  // rank = #{c': e[c'] > e[c]} + #{c'<c: e[c'] == e[c]}  (stable argsort of -e)
  int rank = 0;
  float ec = e[c];
  for (int i = 0; i < 64; ++i) {
    float ei = e[i];
    rank += (ei > ec) || (ei == ec && i < c);
  }
  float mask = (rank < 32) ? 1.f : 0.f;
  my[c] = mx[c] * mask;
  mz[c] = mx[c] * (1.f - mask);
  __syncthreads();
  {
    float l, r, m;
    l = (c > 0) ? mx[c - 1] : 0.f; m = mx[c]; r = (c < 63) ? mx[c + 1] : 0.f;
    ax[c] = sigm_f(ex_w[0] * l + ex_w[1] * m + ex_w[2] * r);
    l = (c > 0) ? my[c - 1] : 0.f; m = my[c]; r = (c < 63) ? my[c + 1] : 0.f;
    ay[c] = sigm_f(ey_w[0] * l + ey_w[1] * m + ey_w[2] * r);
    l = (c > 0) ? mz[c - 1] : 0.f; m = mz[c]; r = (c < 63) ? mz[c + 1] : 0.f;
    az[c] = sigm_f(ez_w[0] * l + ez_w[1] * m + ez_w[2] * r);
  }
  __syncthreads();
  // a_f: grouped 1x1 on concat([a_y, a_z]); group g reads concat chans [g*32, g*32+32)
  {
    int g = c >> 4;
    float acc = ff_b[c];
#pragma unroll
    for (int i = 0; i < 32; ++i) {
      int ch = g * 32 + i;
      float v = (ch < 64) ? ay[ch] : az[ch - 64];
      acc = fmaf(v, ff_w[c * 32 + i], acc);
    }
    af[c] = acc;
  }
  __syncthreads();
  if (c < 16) {
    float a = g1_b[c];
#pragma unroll
    for (int i = 0; i < 64; ++i) a = fmaf(af[i], g1_w[c * 128 + i], a);
#pragma unroll
    for (int i = 0; i < 64; ++i) a = fmaf(ax[i], g1_w[c * 128 + 64 + i], a);
    h1[c] = silu_f(a);
  }
  __syncthreads();
  float gv = g2_b[c];
#pragma unroll
  for (int o = 0; o < 16; ++o) gv = fmaf(h1[o], g2_w[c * 16 + o], gv);
  gv = sigm_f(gv);
  s2[b * 64 + c] = gv * af[c] + (1.f - gv) * ax[c];
}

// ---------------------------------------------------------------------------
// Kernel C: fused ReceptiveFieldAttentionConv.
// Pixel-shuffle + stride-3 conv == per-pixel reduction over (ic_in_group, j).
// Block = (b, group g of 16 ch, tile of 4 rows); thread = pixel.
// ---------------------------------------------------------------------------
__global__ __launch_bounds__(256) void k_rfa(
    const float* __restrict__ x,
    const float* __restrict__ sc_w, const float* __restrict__ sc_b,
    const float* __restrict__ ac_w, const float* __restrict__ ac_b,
    const float* __restrict__ oc_w, const float* __restrict__ oc_b,
    const float* __restrict__ bn_g, const float* __restrict__ bn_b,
    const float* __restrict__ bn_m, const float* __restrict__ bn_v,
    float* __restrict__ xrfa) {
  __shared__ float scw_l[1296];
  __shared__ float scb_l[144];
  __shared__ float acw_l[144];
  __shared__ float acb_l[144];
  __shared__ float ocw_l[2304];
  __shared__ float ocb_l[16];
  __shared__ float bns_l[16];
  __shared__ float bnb_l[16];
  const int blk = blockIdx.x;
  const int tile = blk & 15;
  const int g = (blk >> 4) & 3;
  const int b = blk >> 6;
  const int tid = threadIdx.x;
  for (int i = tid; i < 1296; i += 256) scw_l[i] = sc_w[g * 1296 + i];
  if (tid < 144) {
    scb_l[tid] = sc_b[g * 144 + tid];
    acw_l[tid] = ac_w[g * 144 + tid];
    acb_l[tid] = ac_b[g * 144 + tid];
  }
  for (int i = tid; i < 2304; i += 256) ocw_l[i] = oc_w[g * 2304 + i];
  if (tid < 16) {
    int oc = g * 16 + tid;
    float s = bn_g[oc] * rsqrtf(bn_v[oc] + EPS);
    bns_l[tid] = s;
    bnb_l[tid] = bn_b[oc] - bn_m[oc] * s;
    ocb_l[tid] = oc_b[oc];
  }
  __syncthreads();
  const int h = tile * 4 + (tid >> 6);
  const int w = tid & 63;
  float acc[16];
#pragma unroll
  for (int i = 0; i < 16; ++i) acc[i] = 0.f;
  const bool tN = h > 0, tS = h < 63, tW = w > 0, tE = w < 63;
  const float* xb = x + ((size_t)(b * 64 + g * 16)) * 4096 + h * 64 + w;
#pragma unroll 1
  for (int icg = 0; icg < 16; ++icg) {
    const float* xc = xb + icg * 4096;
    float nb[9];
    nb[0] = (tN && tW) ? xc[-65] : 0.f;
    nb[1] = tN ? xc[-64] : 0.f;
    nb[2] = (tN && tE) ? xc[-63] : 0.f;
    nb[3] = tW ? xc[-1] : 0.f;
    nb[4] = xc[0];
    nb[5] = tE ? xc[1] : 0.f;
    nb[6] = (tS && tW) ? xc[63] : 0.f;
    nb[7] = tS ? xc[64] : 0.f;
    nb[8] = (tS && tE) ? xc[65] : 0.f;
    float ap = (nb[0] + nb[1] + nb[2] + nb[3] + nb[4] + nb[5] + nb[6] + nb[7] + nb[8]) * (1.f / 9.f);
    float f[9], a[9];
    float amax = -1e30f;
#pragma unroll
    for (int j = 0; j < 9; ++j) {
      const float* wj = &scw_l[(icg * 9 + j) * 9];
      float pre = scb_l[icg * 9 + j];
#pragma unroll
      for (int t = 0; t < 9; ++t) pre = fmaf(nb[t], wj[t], pre);
      f[j] = silu_f(pre);
      float av = fmaf(ap, acw_l[icg * 9 + j], acb_l[icg * 9 + j]);
      a[j] = av;
      amax = fmaxf(amax, av);
    }
    float esum = 0.f;
    float p[9];
#pragma unroll
    for (int j = 0; j < 9; ++j) {
      float ev = __expf(a[j] - amax);
      esum += ev;
      p[j] = f[j] * ev;
    }
    float inv = 1.f / esum;
#pragma unroll
    for (int j = 0; j < 9; ++j) p[j] *= inv;
#pragma unroll
    for (int oco = 0; oco < 16; ++oco) {
      const float* wv = &ocw_l[(oco * 16 + icg) * 9];
      float s = 0.f;
#pragma unroll
      for (int j = 0; j < 9; ++j) s = fmaf(p[j], wv[j], s);
      acc[oco] += s;
    }
  }
  float* op = xrfa + ((size_t)(b * 64 + g * 16)) * 4096 + h * 64 + w;
#pragma unroll
  for (int oco = 0; oco < 16; ++oco) {
    float v = acc[oco] + ocb_l[oco];
    v = fmaf(v, bns_l[oco], bnb_l[oco]);
    op[oco * 4096] = silu_f(v);
  }
}

// ---------------------------------------------------------------------------
// Kernel D: final 1x1 conv over concat([x_rfa, x*s2]) + BN + SiLU.
// ---------------------------------------------------------------------------
__global__ __launch_bounds__(128) void k_fuse(
    const float* __restrict__ x, const float* __restrict__ xrfa,
    const float* __restrict__ s2, const float* __restrict__ fu_w,
    const float* __restrict__ fu_b, const float* __restrict__ bn_g,
    const float* __restrict__ bn_b, const float* __restrict__ bn_m,
    const float* __restrict__ bn_v, float* __restrict__ out) {
  __shared__ float fw[4096];
  __shared__ float s2l[64];
  __shared__ float fub[32], bns[32], bnb[32];
  const int blk = blockIdx.x;
  const int tile = blk & 31;
  const int b = blk >> 5;
  const int tid = threadIdx.x;
  for (int i = tid; i < 4096; i += 128) fw[i] = fu_w[i];
  if (tid < 64) s2l[tid] = s2[b * 64 + tid];
  if (tid < 32) {
    float s = bn_g[tid] * rsqrtf(bn_v[tid] + EPS);
    bns[tid] = s;
    bnb[tid] = bn_b[tid] - bn_m[tid] * s;
    fub[tid] = fu_b[tid];
  }
  __syncthreads();
  const int h = tile * 2 + (tid >> 6);
  const int w = tid & 63;
  const int sp = h * 64 + w;
  float acc[32];
#pragma unroll
  for (int i = 0; i < 32; ++i) acc[i] = 0.f;
  const float* xr = xrfa + (size_t)b * 64 * 4096 + sp;
  const float* xp = x + (size_t)b * 64 * 4096 + sp;
#pragma unroll 4
  for (int c = 0; c < 64; ++c) {
    float v = xr[c * 4096];
#pragma unroll
    for (int oc = 0; oc < 32; ++oc) acc[oc] = fmaf(v, fw[oc * 128 + c], acc[oc]);
  }
#pragma unroll 4
  for (int c = 0; c < 64; ++c) {
    float v = xp[c * 4096] * s2l[c];
#pragma unroll
    for (int oc = 0; oc < 32; ++oc) acc[oc] = fmaf(v, fw[oc * 128 + 64 + c], acc[oc]);
  }
  float* op = out + (size_t)b * 32 * 4096 + sp;
#pragma unroll
  for (int oc = 0; oc < 32; ++oc) {
    float v = acc[oc] + fub[oc];
    v = fmaf(v, bns[oc], bnb[oc]);
    op[oc * 4096] = silu_f(v);
  }
}

extern "C" void kernel_launch(void* const* d_in, const int* in_sizes, int n_in,
                              void* d_out, int out_size, void* d_ws, size_t ws_size,
                              hipStream_t stream) {
  const float* x       = (const float*)d_in[0];
  const float* sc_w    = (const float*)d_in[1];
  const float* sc_b    = (const float*)d_in[2];
  const float* ac_w    = (const float*)d_in[3];
  const float* ac_b    = (const float*)d_in[4];
  const float* oc_w    = (const float*)d_in[5];
  const float* oc_b    = (const float*)d_in[6];
  const float* oc_bn_g = (const float*)d_in[7];
  const float* oc_bn_b = (const float*)d_in[8];
  const float* oc_bn_m = (const float*)d_in[9];
  const float* oc_bn_v = (const float*)d_in[10];
  const float* ex_w    = (const float*)d_in[11];
  const float* ey_w    = (const float*)d_in[12];
  const float* ez_w    = (const float*)d_in[13];
  const float* ff_w    = (const float*)d_in[14];
  const float* ff_b    = (const float*)d_in[15];
  const float* g1_w    = (const float*)d_in[16];
  const float* g1_b    = (const float*)d_in[17];
  const float* g2_w    = (const float*)d_in[18];
  const float* g2_b    = (const float*)d_in[19];
  const float* fu_w    = (const float*)d_in[20];
  const float* fu_b    = (const float*)d_in[21];
  const float* fu_bn_g = (const float*)d_in[22];
  const float* fu_bn_b = (const float*)d_in[23];
  const float* fu_bn_m = (const float*)d_in[24];
  const float* fu_bn_v = (const float*)d_in[25];

  float* ws     = (float*)d_ws;
  float* energy = ws;            // 512 floats
  float* meanx  = ws + 512;      // 512 floats
  float* s2     = ws + 1024;     // 512 floats
  float* xrfa   = ws + 2048;     // 8*64*4096 = 2097152 floats

  k_dft<<<512, 256, 0, stream>>>(x, energy, meanx);
  k_attn<<<8, 64, 0, stream>>>(energy, meanx, ex_w, ey_w, ez_w,
                               ff_w, ff_b, g1_w, g1_b, g2_w, g2_b, s2);
  k_rfa<<<512, 256, 0, stream>>>(x, sc_w, sc_b, ac_w, ac_b, oc_w, oc_b,
                                 oc_bn_g, oc_bn_b, oc_bn_m, oc_bn_v, xrfa);
  k_fuse<<<256, 128, 0, stream>>>(x, xrfa, s2, fu_w, fu_b,
                                  fu_bn_g, fu_bn_b, fu_bn_m, fu_bn_v,
                                  (float*)d_out);
}

// Round 3
// 204.467 us; speedup vs baseline: 1.5255x; 1.0947x over previous
//
#include <hip/hip_runtime.h>
#include <math.h>

#define EPS 1e-5f

__device__ __forceinline__ float wave_sum(float v) {
  v += __shfl_down(v, 32);
  v += __shfl_down(v, 16);
  v += __shfl_down(v, 8);
  v += __shfl_down(v, 4);
  v += __shfl_down(v, 2);
  v += __shfl_down(v, 1);
  return v;
}

__device__ __forceinline__ float silu_f(float v) { return v / (1.f + __expf(-v)); }
__device__ __forceinline__ float sigm_f(float v) { return 1.f / (1.f + __expf(-v)); }

// ---------------------------------------------------------------------------
// Kernel A: per-(b,c) mean |2D-DFT| + spatial mean, via wave-level radix-2
// DIF FFT (unchanged from R1; ~10 us).
// ---------------------------------------------------------------------------
__global__ __launch_bounds__(256) void k_dft(const float* __restrict__ x,
                                             float* __restrict__ energy,
                                             float* __restrict__ meanx) {
  __shared__ float re1[64 * 65];
  __shared__ float im1[64 * 65];
  __shared__ float redA[4], redB[4];
  const int bc = blockIdx.x;       // b*64 + c
  const int tid = threadIdx.x;
  const int lane = tid & 63;
  const int wv = tid >> 6;         // wave 0..3
  const float* xp = x + (size_t)bc * 4096;

  float twc[6], tws[6];
#pragma unroll
  for (int s = 0; s < 6; ++s) {
    int half = 32 >> s;
    if (lane & half) {
      float ang = -6.283185307179586f * (float)((lane & (half - 1)) << s) / 64.f;
      float sv, cv;
      __sincosf(ang, &sv, &cv);
      twc[s] = cv;
      tws[s] = sv;
    } else {
      twc[s] = 1.f;
      tws[s] = 0.f;
    }
  }

  float lsum = 0.f;
#pragma unroll 1
  for (int rp = 0; rp < 8; ++rp) {
    const int h0 = wv * 16 + rp * 2;
    float ar = xp[h0 * 64 + lane];
    float br = xp[(h0 + 1) * 64 + lane];
    lsum += ar + br;
    float ai = 0.f, bi = 0.f;
#pragma unroll
    for (int s = 0; s < 6; ++s) {
      const int half = 32 >> s;
      const bool up = (lane & half) != 0;
      float par = __shfl_xor(ar, half);
      float pai = __shfl_xor(ai, half);
      float pbr = __shfl_xor(br, half);
      float pbi = __shfl_xor(bi, half);
      float tar = up ? par - ar : ar + par;
      float tai = up ? pai - ai : ai + pai;
      float tbr = up ? pbr - br : br + pbr;
      float tbi = up ? pbi - bi : bi + pbi;
      const float c = twc[s], sn = tws[s];
      ar = tar * c - tai * sn;
      ai = tar * sn + tai * c;
      br = tbr * c - tbi * sn;
      bi = tbr * sn + tbi * c;
    }
    re1[lane * 65 + h0] = ar;
    im1[lane * 65 + h0] = ai;
    re1[lane * 65 + h0 + 1] = br;
    im1[lane * 65 + h0 + 1] = bi;
  }
  __syncthreads();

  float msum = 0.f;
#pragma unroll 1
  for (int cp = 0; cp < 8; ++cp) {
    const int c0 = wv * 16 + cp * 2;
    float ar = re1[c0 * 65 + lane];
    float ai = im1[c0 * 65 + lane];
    float br = re1[(c0 + 1) * 65 + lane];
    float bi = im1[(c0 + 1) * 65 + lane];
#pragma unroll
    for (int s = 0; s < 6; ++s) {
      const int half = 32 >> s;
      const bool up = (lane & half) != 0;
      float par = __shfl_xor(ar, half);
      float pai = __shfl_xor(ai, half);
      float pbr = __shfl_xor(br, half);
      float pbi = __shfl_xor(bi, half);
      float tar = up ? par - ar : ar + par;
      float tai = up ? pai - ai : ai + pai;
      float tbr = up ? pbr - br : br + pbr;
      float tbi = up ? pbi - bi : bi + pbi;
      const float c = twc[s], sn = tws[s];
      ar = tar * c - tai * sn;
      ai = tar * sn + tai * c;
      br = tbr * c - tbi * sn;
      bi = tbr * sn + tbi * c;
    }
    msum += sqrtf(ar * ar + ai * ai) + sqrtf(br * br + bi * bi);
  }

  msum = wave_sum(msum);
  lsum = wave_sum(lsum);
  if (lane == 0) { redA[wv] = msum; redB[wv] = lsum; }
  __syncthreads();
  if (tid == 0) {
    float e = redA[0] + redA[1] + redA[2] + redA[3];
    float m = redB[0] + redB[1] + redB[2] + redB[3];
    energy[bc] = e * (1.f / 4096.f);
    meanx[bc] = m * (1.f / 4096.f);
  }
}

// ---------------------------------------------------------------------------
// Kernel B: per-batch channel attention head (unchanged).
// ---------------------------------------------------------------------------
__global__ __launch_bounds__(64) void k_attn(
    const float* __restrict__ energy, const float* __restrict__ meanx,
    const float* __restrict__ ex_w, const float* __restrict__ ey_w,
    const float* __restrict__ ez_w, const float* __restrict__ ff_w,
    const float* __restrict__ ff_b, const float* __restrict__ g1_w,
    const float* __restrict__ g1_b, const float* __restrict__ g2_w,
    const float* __restrict__ g2_b, float* __restrict__ s2) {
  __shared__ float e[64], mx[64], my[64], mz[64];
  __shared__ float ax[64], ay[64], az[64], af[64], h1[16];
  const int b = blockIdx.x;
  const int c = threadIdx.x;
  e[c] = energy[b * 64 + c];
  mx[c] = meanx[b * 64 + c];
  __syncthreads();
  int rank = 0;
  float ec = e[c];
  for (int i = 0; i < 64; ++i) {
    float ei = e[i];
    rank += (ei > ec) || (ei == ec && i < c);
  }
  float mask = (rank < 32) ? 1.f : 0.f;
  my[c] = mx[c] * mask;
  mz[c] = mx[c] * (1.f - mask);
  __syncthreads();
  {
    float l, r, m;
    l = (c > 0) ? mx[c - 1] : 0.f; m = mx[c]; r = (c < 63) ? mx[c + 1] : 0.f;
    ax[c] = sigm_f(ex_w[0] * l + ex_w[1] * m + ex_w[2] * r);
    l = (c > 0) ? my[c - 1] : 0.f; m = my[c]; r = (c < 63) ? my[c + 1] : 0.f;
    ay[c] = sigm_f(ey_w[0] * l + ey_w[1] * m + ey_w[2] * r);
    l = (c > 0) ? mz[c - 1] : 0.f; m = mz[c]; r = (c < 63) ? mz[c + 1] : 0.f;
    az[c] = sigm_f(ez_w[0] * l + ez_w[1] * m + ez_w[2] * r);
  }
  __syncthreads();
  {
    int g = c >> 4;
    float acc = ff_b[c];
#pragma unroll
    for (int i = 0; i < 32; ++i) {
      int ch = g * 32 + i;
      float v = (ch < 64) ? ay[ch] : az[ch - 64];
      acc = fmaf(v, ff_w[c * 32 + i], acc);
    }
    af[c] = acc;
  }
  __syncthreads();
  if (c < 16) {
    float a = g1_b[c];
#pragma unroll
    for (int i = 0; i < 64; ++i) a = fmaf(af[i], g1_w[c * 128 + i], a);
#pragma unroll
    for (int i = 0; i < 64; ++i) a = fmaf(ax[i], g1_w[c * 128 + 64 + i], a);
    h1[c] = silu_f(a);
  }
  __syncthreads();
  float gv = g2_b[c];
#pragma unroll
  for (int o = 0; o < 16; ++o) gv = fmaf(h1[o], g2_w[c * 16 + o], gv);
  gv = sigm_f(gv);
  s2[b * 64 + c] = gv * af[c] + (1.f - gv) * ax[c];
}

// ---------------------------------------------------------------------------
// Kernel C: fused ReceptiveFieldAttentionConv.
// R2: weights via SCALAR loads (wave-uniform global indices -> s_load + SGPR
// operand in v_fma); x neighborhood from zero-padded LDS tile with immediate
// ds offsets (no bounds predication in the hot loop).
// ---------------------------------------------------------------------------
__global__ __launch_bounds__(256) void k_rfa(
    const float* __restrict__ x,
    const float* __restrict__ sc_w, const float* __restrict__ sc_b,
    const float* __restrict__ ac_w, const float* __restrict__ ac_b,
    const float* __restrict__ oc_w, const float* __restrict__ oc_b,
    const float* __restrict__ bn_g, const float* __restrict__ bn_b,
    const float* __restrict__ bn_m, const float* __restrict__ bn_v,
    float* __restrict__ xrfa) {
  __shared__ float xs[16 * 6 * 66];   // [ch][6 rows][66 cols], zero borders
  const int blk = blockIdx.x;
  const int tile = blk & 15;
  const int g = (blk >> 4) & 3;
  const int b = blk >> 6;
  const int tid = threadIdx.x;
  const int lane = tid & 63;
  const int wv = tid >> 6;
  const int h0 = tile * 4;

  // stage interior: 96 (ch,row) pairs x 64 cols, coalesced
  for (int p = wv; p < 96; p += 4) {
    int ch = p / 6, lrow = p - ch * 6;
    int h = h0 - 1 + lrow;
    float v = 0.f;
    if (h >= 0 && h < 64)
      v = x[((size_t)(b * 64 + g * 16 + ch)) * 4096 + h * 64 + lane];
    xs[ch * 396 + lrow * 66 + lane + 1] = v;
  }
  // zero left/right border columns: 16*6*2 = 192 slots
  if (tid < 192) {
    int ch = tid / 12;
    int rem = tid - ch * 12;
    int r = rem >> 1;
    int cc = (tid & 1) * 65;
    xs[ch * 396 + r * 66 + cc] = 0.f;
  }
  __syncthreads();

  const int tr = wv;          // row in tile (0..3)
  const int w = lane;         // col
  const float* scw = sc_w + g * 1296;
  const float* scbp = sc_b + g * 144;
  const float* acwp = ac_w + g * 144;
  const float* acbp = ac_b + g * 144;
  const float* ocwp = oc_w + g * 2304;

  float acc[16];
#pragma unroll
  for (int i = 0; i < 16; ++i) acc[i] = 0.f;
  const int base0 = tr * 66 + w;

#pragma unroll 1
  for (int icg = 0; icg < 16; ++icg) {
    const float* xsp = &xs[icg * 396 + base0];
    float nb[9];
#pragma unroll
    for (int dr = 0; dr < 3; ++dr)
#pragma unroll
      for (int dc = 0; dc < 3; ++dc)
        nb[dr * 3 + dc] = xsp[dr * 66 + dc];
    float ap = (nb[0] + nb[1] + nb[2] + nb[3] + nb[4] + nb[5] + nb[6] + nb[7] + nb[8]) * (1.f / 9.f);
    float f[9], a[9];
    float amax = -1e30f;
#pragma unroll
    for (int j = 0; j < 9; ++j) {
      float pre = scbp[icg * 9 + j];
#pragma unroll
      for (int t = 0; t < 9; ++t) pre = fmaf(nb[t], scw[(icg * 9 + j) * 9 + t], pre);
      f[j] = silu_f(pre);
      float av = fmaf(ap, acwp[icg * 9 + j], acbp[icg * 9 + j]);
      a[j] = av;
      amax = fmaxf(amax, av);
    }
    float esum = 0.f;
    float p[9];
#pragma unroll
    for (int j = 0; j < 9; ++j) {
      float ev = __expf(a[j] - amax);
      esum += ev;
      p[j] = f[j] * ev;
    }
    float inv = __fdividef(1.f, esum);
#pragma unroll
    for (int j = 0; j < 9; ++j) p[j] *= inv;
#pragma unroll
    for (int oco = 0; oco < 16; ++oco) {
      float s = 0.f;
#pragma unroll
      for (int j = 0; j < 9; ++j) s = fmaf(p[j], ocwp[(oco * 16 + icg) * 9 + j], s);
      acc[oco] += s;
    }
  }

  float* op = xrfa + ((size_t)(b * 64 + g * 16)) * 4096 + (h0 + tr) * 64 + w;
#pragma unroll
  for (int oco = 0; oco < 16; ++oco) {
    int oc = g * 16 + oco;
    float s = bn_g[oc] * rsqrtf(bn_v[oc] + EPS);
    float v = acc[oco] + oc_b[oc];
    v = fmaf(v, s, bn_b[oc] - bn_m[oc] * s);
    op[oco * 4096] = silu_f(v);
  }
}

// ---------------------------------------------------------------------------
// Kernel D: final 1x1 conv + BN + SiLU.
// R2: 512 blocks x 256 thr; block = 64 sites x 4 c-chunks; inputs in 32
// VGPRs, weights via scalar loads (contiguous in inner index), LDS stride-33
// partial-sum reduction (conflict-free).
// ---------------------------------------------------------------------------
__global__ __launch_bounds__(256) void k_fuse(
    const float* __restrict__ x, const float* __restrict__ xrfa,
    const float* __restrict__ s2, const float* __restrict__ fu_w,
    const float* __restrict__ fu_b, const float* __restrict__ bn_g,
    const float* __restrict__ bn_b, const float* __restrict__ bn_m,
    const float* __restrict__ bn_v, float* __restrict__ out) {
  __shared__ float red[3 * 64 * 33];   // 6336 floats
  const int blk = blockIdx.x;          // 512 blocks
  const int tid = threadIdx.x;
  const int sloc = tid & 63;
  const int chunk = __builtin_amdgcn_readfirstlane(tid >> 6);  // wave-uniform
  const int b = blk >> 6;
  const int sp = (blk & 63) * 64 + sloc;
  const int cb = (chunk & 1) * 32;     // input channel base within source
  const int wb = chunk * 32;           // fw column base

  const float* src = (chunk < 2) ? xrfa : x;
  const float* ip = src + ((size_t)(b * 64 + cb)) * 4096 + sp;
  float inv[32];
  if (chunk < 2) {
#pragma unroll
    for (int i = 0; i < 32; ++i) inv[i] = ip[i * 4096];
  } else {
#pragma unroll
    for (int i = 0; i < 32; ++i) inv[i] = ip[i * 4096] * s2[b * 64 + cb + i];
  }

  float acc[32];
#pragma unroll
  for (int oc = 0; oc < 32; ++oc) {
    float a = 0.f;
#pragma unroll
    for (int i = 0; i < 32; ++i) a = fmaf(inv[i], fu_w[oc * 128 + wb + i], a);
    acc[oc] = a;
  }

  if (chunk != 0) {
    float* rp = &red[(chunk - 1) * 2112 + sloc * 33];
#pragma unroll
    for (int oc = 0; oc < 32; ++oc) rp[oc] = acc[oc];
  }
  __syncthreads();
  if (chunk == 0) {
#pragma unroll
    for (int oc = 0; oc < 32; ++oc)
      acc[oc] += red[sloc * 33 + oc] + red[2112 + sloc * 33 + oc] +
                 red[4224 + sloc * 33 + oc];
    float* op = out + ((size_t)b * 32) * 4096 + sp;
#pragma unroll
    for (int oc = 0; oc < 32; ++oc) {
      float s = bn_g[oc] * rsqrtf(bn_v[oc] + EPS);
      float v = acc[oc] + fu_b[oc];
      v = fmaf(v, s, bn_b[oc] - bn_m[oc] * s);
      op[oc * 4096] = silu_f(v);
    }
  }
}

extern "C" void kernel_launch(void* const* d_in, const int* in_sizes, int n_in,
                              void* d_out, int out_size, void* d_ws, size_t ws_size,
                              hipStream_t stream) {
  const float* x       = (const float*)d_in[0];
  const float* sc_w    = (const float*)d_in[1];
  const float* sc_b    = (const float*)d_in[2];
  const float* ac_w    = (const float*)d_in[3];
  const float* ac_b    = (const float*)d_in[4];
  const float* oc_w    = (const float*)d_in[5];
  const float* oc_b    = (const float*)d_in[6];
  const float* oc_bn_g = (const float*)d_in[7];
  const float* oc_bn_b = (const float*)d_in[8];
  const float* oc_bn_m = (const float*)d_in[9];
  const float* oc_bn_v = (const float*)d_in[10];
  const float* ex_w    = (const float*)d_in[11];
  const float* ey_w    = (const float*)d_in[12];
  const float* ez_w    = (const float*)d_in[13];
  const float* ff_w    = (const float*)d_in[14];
  const float* ff_b    = (const float*)d_in[15];
  const float* g1_w    = (const float*)d_in[16];
  const float* g1_b    = (const float*)d_in[17];
  const float* g2_w    = (const float*)d_in[18];
  const float* g2_b    = (const float*)d_in[19];
  const float* fu_w    = (const float*)d_in[20];
  const float* fu_b    = (const float*)d_in[21];
  const float* fu_bn_g = (const float*)d_in[22];
  const float* fu_bn_b = (const float*)d_in[23];
  const float* fu_bn_m = (const float*)d_in[24];
  const float* fu_bn_v = (const float*)d_in[25];

  float* ws     = (float*)d_ws;
  float* energy = ws;            // 512 floats
  float* meanx  = ws + 512;      // 512 floats
  float* s2     = ws + 1024;     // 512 floats
  float* xrfa   = ws + 2048;     // 8*64*4096 floats

  k_dft<<<512, 256, 0, stream>>>(x, energy, meanx);
  k_attn<<<8, 64, 0, stream>>>(energy, meanx, ex_w, ey_w, ez_w,
                               ff_w, ff_b, g1_w, g1_b, g2_w, g2_b, s2);
  k_rfa<<<512, 256, 0, stream>>>(x, sc_w, sc_b, ac_w, ac_b, oc_w, oc_b,
                                 oc_bn_g, oc_bn_b, oc_bn_m, oc_bn_v, xrfa);
  k_fuse<<<512, 256, 0, stream>>>(x, xrfa, s2, fu_w, fu_b,
                                  fu_bn_g, fu_bn_b, fu_bn_m, fu_bn_v,
                                  (float*)d_out);
}